// Round 1
// 110.794 us; speedup vs baseline: 1.0186x; 1.0186x over previous
//
#include <hip/hip_runtime.h>
#include <hip/hip_fp16.h>

#define HH 512
#define WD 512
#define HP 514
#define BN 8
#define CN 3

#define TH 16
#define TW 32

// LDS tiles. sp4 is channel-packed float4 (.xyz = ch0..2) so one tap = one
// 16B-aligned ds_read_b128. sr/swm scalar with odd pitch (conflict-free).
// w9: per-WM-pixel cache of the 9 Gaussian weights computed in phase 2,
// stored fp16 (20B/px, 5-dword stride -> 2-way bank aliasing = free), so
// phase 3 never recomputes window stats.
#define SP_ROWS (TH + 6)          // 22  img_p rows [h0-2, h0+20)
#define SP_COLS (TW + 6)          // 38
#define SR_ROWS (TH + 4)          // 20  img_r rows [h0-2, h0+18)
#define SR_COLS (TW + 4)          // 36
#define SR_PITCH (SR_COLS + 1)    // 37
#define WM_ROWS (TH + 2)          // 18  w_mod rows [h0-1, h0+17)
#define WM_COLS (TW + 2)          // 34
#define WM_PITCH (WM_COLS + 1)    // 35
#define W9_STRIDE 10              // halves per pixel (9 used, 1 pad -> 20 B)

// Robust per-batch flag read: contract says int32, hedge for bool bytes.
__device__ __forceinline__ int load_flag(const int* __restrict__ p, int b) {
    bool all01 = true;
#pragma unroll
    for (int i = 0; i < BN; ++i) {
        int v = p[i];
        all01 = all01 && (v == 0 || v == 1);
    }
    if (all01) return p[b];
    const unsigned char* pb = (const unsigned char*)p;
    return pb[b] != 0;
}

__device__ __forceinline__ float fast_rcp(float x) {
    return __builtin_amdgcn_rcpf(x);
}

// Phase-2 per-pixel body. col is a rotating 3-column register buffer:
// window column j of pixel P lives in slot (j+P)%3 (all indices are
// compile-time constants after unrolling -> stays in VGPRs, rule #20).
// Math is kept in the exact accumulation order of the previous version.
template <int P>
__device__ __forceinline__ void p2_pixel(const float4 (&col)[3][3], int r, int cc,
                                         bool hok, int w,
                                         float* __restrict__ sr,
                                         __half* __restrict__ w9) {
    float val = 0.f;
    if (hok && (unsigned)w < (unsigned)WD) {
        float sx = 0.f, sy = 0.f, sz = 0.f;
#pragma unroll
        for (int k = 0; k < 9; ++k) {
            const float4 tp = col[(k % 3 + P) % 3][k / 3];
            sx += tp.x; sy += tp.y; sz += tp.z;
        }
        float mx = sx * (1.f / 9.f), my = sy * (1.f / 9.f), mz = sz * (1.f / 9.f);
        float sdx = 0.f, sdy = 0.f, sdz = 0.f;
#pragma unroll
        for (int k = 0; k < 9; ++k) {
            const float4 tp = col[(k % 3 + P) % 3][k / 3];
            float dx = tp.x - mx, dy = tp.y - my, dz = tp.z - mz;
            sdx += dx * dx; sdy += dy * dy; sdz += dz * dz;
        }
        float ivx = 4.f * fast_rcp(sdx);  // 1/(2*var), var = sd/8 (ddof=1)
        float ivy = 4.f * fast_rcp(sdy);
        float ivz = 4.f * fast_rcp(sdz);
        float wk[9];
        float num = 0.f, den = 0.f;
#pragma unroll
        for (int k = 0; k < 9; ++k) {
            const float4 tp = col[(k % 3 + P) % 3][k / 3];
            float dx = tp.x - mx, dy = tp.y - my, dz = tp.z - mz;
            float txx = dx * dx * ivx, tyy = dy * dy * ivy, tzz = dz * dz * ivz;
            float m = fmaxf(txx, fmaxf(tyy, tzz));
            wk[k] = __expf(-m);
            num += (tp.x + tp.y + tp.z) * wk[k];
            den += wk[k];
        }
        val = num * fast_rcp(den);
        // cache the 9 weights (fp16, packed dword writes) for phase 3
        if (r >= 1 && r < SR_ROWS - 1 && cc >= 1 && cc < SR_COLS - 1) {
            int pix = (r - 1) * WM_COLS + (cc - 1);
            unsigned int* wp = (unsigned int*)&w9[pix * W9_STRIDE];
#pragma unroll
            for (int k = 0; k < 4; ++k) {
                __half2 h2 = __floats2half2_rn(wk[2 * k], wk[2 * k + 1]);
                wp[k] = *(unsigned int*)&h2;
            }
            w9[pix * W9_STRIDE + 8] = __float2half_rn(wk[8]);
        }
    }
    sr[r * SR_PITCH + cc] = val;
}

__global__ __launch_bounds__(256) void fused(const float* __restrict__ img,
                                             const float* __restrict__ noise,
                                             const int* __restrict__ ids_sel,
                                             const int* __restrict__ ids_dil,
                                             int* __restrict__ out) {
    // XCD-aware swizzle (8 XCDs, dispatch round-robins lin%8). Each XCD gets
    // a contiguous 64-tile band (4 tile rows, ~1.7 MB working set < 4 MB L2)
    // from EVERY batch, band index rotated by batch so cheap copy-batches are
    // spread evenly across XCDs (load balance). Bijective: 4096 = 8*8*64.
    int lin = blockIdx.x + 16 * blockIdx.y + 512 * blockIdx.z;
    int xcd = lin & 7;
    int m = lin >> 3;            // 0..511 sequence within this XCD
    int b = m >> 6;              // batch 0..7
    int within = m & 63;         // 0..63 tile within band
    int band = (xcd + b) & 7;    // rotate bands across batches
    int tl = band * 64 + within; // tile id within batch, row-major x-fastest
    int by = tl >> 4, bx = tl & 15;
    int h0 = by * TH, w0 = bx * TW;
    int t = threadIdx.x;

    if (!load_flag(ids_sel, b)) {  // uniform per block: plain uint8 copy, 2 px/thread
        int r = t >> 4, lx = (t & 15) << 1;
#pragma unroll
        for (int c = 0; c < CN; ++c) {
            const float* im = img + (size_t)(b * CN + c) * HH * WD;
            int* op = out + (size_t)(b * CN + c) * HH * WD;
            float2 v = *(const float2*)&im[(h0 + r) * WD + w0 + lx];
            int2 ov;
            ov.x = ((int)v.x) & 255;
            ov.y = ((int)v.y) & 255;
            __builtin_nontemporal_store(*(const long long*)&ov,
                                        (long long*)&op[(h0 + r) * WD + w0 + lx]);
        }
        return;
    }
    bool dil = load_flag(ids_dil, b) != 0;

    __shared__ float4 sp4[SP_ROWS * SP_COLS];               // 13,376 B
    __shared__ float sr[SR_ROWS * SR_PITCH];                //  2,960 B
    __shared__ float swm[WM_ROWS * WM_PITCH];               //  2,520 B
    __shared__ __align__(4) __half w9[WM_ROWS * WM_COLS * W9_STRIDE];  // 12,240 B

    // Phase 1: stage img_p (3ch packed) rows [h0-2,h0+20), cols [w0-2,w0+36).
    // Index-clamped; clamped entries feed only out-of-image pixels (forced 0).
    {
        const float* nz = noise + (size_t)b * CN * HP * HP;
        const float* im = img + (size_t)b * CN * HH * WD;
        for (int idx = t; idx < SP_ROWS * SP_COLS; idx += 256) {
            int r = idx / SP_COLS, cc = idx - r * SP_COLS;
            int ip = h0 - 2 + r, jp = w0 - 2 + cc;
            ip = ip < 0 ? 0 : (ip > HP - 1 ? HP - 1 : ip);
            jp = jp < 0 ? 0 : (jp > HP - 1 ? HP - 1 : jp);
            bool in = (ip >= 1 && ip <= HH && jp >= 1 && jp <= WD);
            int no = ip * HP + jp;
            int io = (ip - 1) * WD + (jp - 1);
            float4 v;
            v.x = nz[no] + (in ? im[io] : 0.f);
            v.y = nz[HP * HP + no] + (in ? im[HH * WD + io] : 0.f);
            v.z = nz[2 * HP * HP + no] + (in ? im[2 * HH * WD + io] : 0.f);
            v.w = 0.f;
            sp4[idx] = v;
        }
    }
    __syncthreads();

    // Phase 2: img_r + w9 cache for rows [h0-2,h0+18), cols [w0-2,w0+34).
    // 240 active threads, 3 consecutive pixels each, sliding 3-column register
    // buffer: 15 ds_read_b128 per 3 px instead of 27 (adjacent windows share
    // 6 of 9 taps).
    if (t < 240) {
        int r = t / 12;            // 0..19
        int s = t - r * 12;        // 0..11
        int cc0 = 3 * s;           // 0,3,..,33
        int h = h0 - 2 + r;
        bool hok = (h >= 0 && h < HH);
        float4 col[3][3];          // [slot][row]
#pragma unroll
        for (int j = 0; j < 3; ++j)
#pragma unroll
            for (int i = 0; i < 3; ++i)
                col[j][i] = sp4[(r + i) * SP_COLS + cc0 + j];
        p2_pixel<0>(col, r, cc0 + 0, hok, w0 - 2 + cc0 + 0, sr, w9);
#pragma unroll
        for (int i = 0; i < 3; ++i) col[0][i] = sp4[(r + i) * SP_COLS + cc0 + 3];
        p2_pixel<1>(col, r, cc0 + 1, hok, w0 - 2 + cc0 + 1, sr, w9);
#pragma unroll
        for (int i = 0; i < 3; ++i) col[1][i] = sp4[(r + i) * SP_COLS + cc0 + 4];
        p2_pixel<2>(col, r, cc0 + 2, hok, w0 - 2 + cc0 + 2, sr, w9);
    }
    __syncthreads();

    // Phase 3: w_mod for pixel rows [h0-1,h0+17), cols [w0-1,w0+33):
    // argmin/argmax over the img_r window, then ONE dynamic LDS u16 read of
    // the cached weight (never a dynamically-indexed register array).
    for (int idx = t; idx < WM_ROWS * WM_COLS; idx += 256) {
        int r = idx / WM_COLS, cc = idx - r * WM_COLS;
        int h = h0 - 1 + r, w = w0 - 1 + cc;
        float wmv = 0.f;
        if (h >= 0 && h < HH && w >= 0 && w < WD) {
            float rv[9];
#pragma unroll
            for (int k = 0; k < 9; ++k)
                rv[k] = sr[(r + k / 3) * SR_PITCH + cc + k % 3];
            int amin = 0, amax = 0;
            float vmin = rv[0], vmax = rv[0];
#pragma unroll
            for (int k = 1; k < 9; ++k) {
                if (rv[k] < vmin) { vmin = rv[k]; amin = k; }  // first occurrence
                if (rv[k] > vmax) { vmax = rv[k]; amax = k; }
            }
            int ksel = dil ? amax : amin;
            wmv = __half2float(w9[idx * W9_STRIDE + ksel]);
        }
        swm[r * WM_PITCH + cc] = wmv;
    }
    __syncthreads();

    // Phase 4: final weighted average, 2 adjacent px per thread (rotating
    // column buffer, 12 b128 taps instead of 18), 3 channels at once, packed
    // dwordx2 nontemporal stores.
    {
        int ly = t >> 4;            // 0..15
        int lx = (t & 15) << 1;     // 0,2,..,30
        float4 c4[3][3];            // [slot][row]
#pragma unroll
        for (int j = 0; j < 3; ++j)
#pragma unroll
            for (int i = 0; i < 3; ++i)
                c4[j][i] = sp4[(ly + 2 + i) * SP_COLS + lx + 2 + j];
        float ws[4][3];
#pragma unroll
        for (int j = 0; j < 4; ++j)
#pragma unroll
            for (int i = 0; i < 3; ++i)
                ws[j][i] = swm[(ly + i) * WM_PITCH + lx + j];
        int2 o0, o1, o2;
        {   // px q=0 at (ly, lx): window col j -> slot j
            float den = 0.f, nx = 0.f, ny = 0.f, nz2 = 0.f;
#pragma unroll
            for (int k = 0; k < 9; ++k) {
                const float wkk = ws[k % 3][k / 3];
                const float4 tp = c4[k % 3][k / 3];
                den += wkk;
                nx += tp.x * wkk; ny += tp.y * wkk; nz2 += tp.z * wkk;
            }
            float rden = 1.f / den;
            o0.x = ((int)(nx * rden)) & 255;
            o1.x = ((int)(ny * rden)) & 255;
            o2.x = ((int)(nz2 * rden)) & 255;
        }
#pragma unroll
        for (int i = 0; i < 3; ++i) c4[0][i] = sp4[(ly + 2 + i) * SP_COLS + lx + 5];
        {   // px q=1 at (ly, lx+1): window col j -> slot (j+1)%3
            float den = 0.f, nx = 0.f, ny = 0.f, nz2 = 0.f;
#pragma unroll
            for (int k = 0; k < 9; ++k) {
                const float wkk = ws[k % 3 + 1][k / 3];
                const float4 tp = c4[(k % 3 + 1) % 3][k / 3];
                den += wkk;
                nx += tp.x * wkk; ny += tp.y * wkk; nz2 += tp.z * wkk;
            }
            float rden = 1.f / den;
            o0.y = ((int)(nx * rden)) & 255;
            o1.y = ((int)(ny * rden)) & 255;
            o2.y = ((int)(nz2 * rden)) & 255;
        }
        size_t o = ((size_t)b * CN * HH + h0 + ly) * WD + w0 + lx;
        __builtin_nontemporal_store(*(const long long*)&o0, (long long*)&out[o]);
        __builtin_nontemporal_store(*(const long long*)&o1,
                                    (long long*)&out[o + (size_t)HH * WD]);
        __builtin_nontemporal_store(*(const long long*)&o2,
                                    (long long*)&out[o + 2 * (size_t)HH * WD]);
    }
}

extern "C" void kernel_launch(void* const* d_in, const int* in_sizes, int n_in,
                              void* d_out, int out_size, void* d_ws, size_t ws_size,
                              hipStream_t stream) {
    const float* img   = (const float*)d_in[0];
    const float* noise = (const float*)d_in[1];
    const int* ids_sel = (const int*)d_in[2];
    const int* ids_dil = (const int*)d_in[3];
    int* out = (int*)d_out;

    dim3 grid(WD / TW, HH / TH, BN);  // 16 x 32 x 8 = 4096 blocks
    fused<<<grid, 256, 0, stream>>>(img, noise, ids_sel, ids_dil, out);
}